// Round 8
// baseline (1121.089 us; speedup 1.0000x reference)
//
#include <hip/hip_runtime.h>
#include <math.h>

#define NB 8
#define NN 2048
#define NM 2048
#define NITERS 50

static constexpr float F_EPS  = 0.005f;
static constexpr float LOG2E  = 1.4426950408889634f;
static constexpr float KK     = LOG2E / F_EPS;      // 288.539...
static constexpr float TWOK   = 2.0f * KK;
static constexpr float NEG_LOG2N = -11.0f;          // -log2(2048)

__device__ __forceinline__ float fexp2(float x) { return __builtin_amdgcn_exp2f(x); }
__device__ __forceinline__ float flog2(float x) { return __builtin_amdgcn_logf(x); }

// ---------------------------------------------------------------------------
// Pack: P[i] = (v0, v1, v2, K*(dual - |v|^2)) with dual = 0.
// ---------------------------------------------------------------------------
__global__ void pack_init(const float* __restrict__ V, float4* __restrict__ Pout, int total)
{
    int i = blockIdx.x * blockDim.x + threadIdx.x;
    if (i < total) {
        float v0 = V[3*i], v1 = V[3*i+1], v2 = V[3*i+2];
        float s  = fmaf(v0, v0, fmaf(v1, v1, v2*v2));
        Pout[i]  = make_float4(v0, v1, v2, -KK * s);
    }
}

// ---------------------------------------------------------------------------
// Sinkhorn half-sweep, 16-rows-per-lane register blocking (2x less cache
// traffic than R7: each loaded float4 feeds 16 z's; 32 KB read per WG).
//   grid = B*N/16 = 1024 WGs x 256 thr, launch_bounds(256,4).
//   Wave w = m-quarter [w*512, +512); lane handles 8 m's (stride 64),
//   ALL 16 rows of the WG. 256 partials/row folded in LDS (two stages,
//   bank-spread). Math identical to verified absmax-0.0 kernels.
// ---------------------------------------------------------------------------
__global__ __launch_bounds__(256, 4) void sink_update(
    const float4* __restrict__ Pin,   // [B][M] packed opposite side
    const float*  __restrict__ Vraw,  // [B][N][3] raw points of side being updated
    float4*       __restrict__ Pout)  // [B][N] packed output
{
    __shared__ float2 part [16][257];  // [row][partial 0..255]
    __shared__ float2 part2[16][17];   // [row][seg 0..15]
    const int tid  = threadIdx.x;
    const int lane = tid & 63;
    const int wave = tid >> 6;          // m-quarter
    const int wgs_per_b = NN / 16;      // 128
    const int b       = blockIdx.x / wgs_per_b;
    const int rowbase = (blockIdx.x % wgs_per_b) * 16;

    float xs0[16], xs1[16], xs2[16];
    {
        const float* vb = Vraw + ((size_t)(b * NN + rowbase)) * 3;
        #pragma unroll
        for (int r = 0; r < 16; ++r) {
            xs0[r] = TWOK * vb[r*3+0];
            xs1[r] = TWOK * vb[r*3+1];
            xs2[r] = TWOK * vb[r*3+2];
        }
    }

    const float4* __restrict__ pp = Pin + b * NM + wave * 512 + lane;

    float rm[16], rs[16];
    #pragma unroll
    for (int r = 0; r < 16; ++r) { rm[r] = -1e30f; rs[r] = 0.f; }

    #pragma unroll
    for (int ib = 0; ib < 2; ++ib) {    // 2 chunks of 4 m's per lane
        const float4 c0 = pp[(ib*4 + 0) * 64];
        const float4 c1 = pp[(ib*4 + 1) * 64];
        const float4 c2 = pp[(ib*4 + 2) * 64];
        const float4 c3 = pp[(ib*4 + 3) * 64];
        #pragma unroll
        for (int r = 0; r < 16; ++r) {
            const float z0 = fmaf(xs0[r], c0.x, fmaf(xs1[r], c0.y, fmaf(xs2[r], c0.z, c0.w)));
            const float z1 = fmaf(xs0[r], c1.x, fmaf(xs1[r], c1.y, fmaf(xs2[r], c1.z, c1.w)));
            const float z2 = fmaf(xs0[r], c2.x, fmaf(xs1[r], c2.y, fmaf(xs2[r], c2.z, c2.w)));
            const float z3 = fmaf(xs0[r], c3.x, fmaf(xs1[r], c3.y, fmaf(xs2[r], c3.z, c3.w)));
            const float cm = fmaxf(fmaxf(z0, z1), fmaxf(z2, z3));
            const float nm = fmaxf(rm[r], cm);
            const float s  = (fexp2(z0 - nm) + fexp2(z1 - nm))
                           + (fexp2(z2 - nm) + fexp2(z3 - nm));
            rs[r] = fmaf(rs[r], fexp2(rm[r] - nm), s);
            rm[r] = nm;
        }
    }

    #pragma unroll
    for (int r = 0; r < 16; ++r)
        part[r][tid] = make_float2(rm[r], rs[r]);
    __syncthreads();

    {   // stage 2: thread (row=tid&15, seg=tid>>4) folds 16 partials.
        // Adjacent threads hit different rows (pitch 257 -> bank stride 2).
        const int row = tid & 15, seg = tid >> 4;
        float m16 = -1e30f;
        float2 v[16];
        #pragma unroll
        for (int k = 0; k < 16; ++k) { v[k] = part[row][seg*16 + k]; m16 = fmaxf(m16, v[k].x); }
        float s16 = 0.f;
        #pragma unroll
        for (int k = 0; k < 16; ++k) s16 = fmaf(v[k].y, fexp2(v[k].x - m16), s16);
        part2[row][seg] = make_float2(m16, s16);
    }
    __syncthreads();

    if (tid < 16) {   // stage 3: fold 16 segs, write packed output row
        float gm = -1e30f;
        float2 v[16];
        #pragma unroll
        for (int k = 0; k < 16; ++k) { v[k] = part2[tid][k]; gm = fmaxf(gm, v[k].x); }
        float s = 0.f;
        #pragma unroll
        for (int k = 0; k < 16; ++k) s = fmaf(v[k].y, fexp2(v[k].x - gm), s);
        const float lse2 = gm + flog2(s);
        const int n0 = rowbase + tid;
        const float* vp = Vraw + ((size_t)(b * NN + n0)) * 3;
        Pout[b * NN + n0] = make_float4(vp[0], vp[1], vp[2], NEG_LOG2N - lse2);
    }
}

// ---------------------------------------------------------------------------
// Final loss, same 16-row blocking.
// out = (1/B) * sum P*C, P = exp2(Af + Ag + 2K*dot), C = max(|x|^2+|y|^2-2dot,0)
// ---------------------------------------------------------------------------
__global__ __launch_bounds__(256, 4) void final_loss(
    const float4* __restrict__ Px, const float4* __restrict__ Py,
    float* __restrict__ out)
{
    __shared__ float wsum[4];
    const int tid  = threadIdx.x;
    const int lane = tid & 63;
    const int wave = tid >> 6;          // m-quarter
    const int wgs_per_b = NN / 16;
    const int b       = blockIdx.x / wgs_per_b;
    const int rowbase = (blockIdx.x % wgs_per_b) * 16;

    float xr0[16], xr1[16], xr2[16], Af[16], xq[16];
    {
        const float4* xb = Px + b * NN + rowbase;
        #pragma unroll
        for (int r = 0; r < 16; ++r) {
            const float4 xp = xb[r];
            xr0[r] = xp.x; xr1[r] = xp.y; xr2[r] = xp.z; Af[r] = xp.w;
            xq[r]  = fmaf(xp.x, xp.x, fmaf(xp.y, xp.y, xp.z * xp.z));
        }
    }

    const float4* __restrict__ pp = Py + b * NM + wave * 512 + lane;

    float acc = 0.f;
    #pragma unroll
    for (int i = 0; i < 8; ++i) {
        const float4 p = pp[i * 64];
        const float ysq = fmaf(p.x, p.x, fmaf(p.y, p.y, p.z * p.z));
        #pragma unroll
        for (int r = 0; r < 16; ++r) {
            const float dot = fmaf(xr0[r], p.x, fmaf(xr1[r], p.y, xr2[r] * p.z));
            const float cc  = fmaxf(fmaf(-2.f, dot, xq[r] + ysq), 0.f);
            const float zp  = fmaf(TWOK, dot, Af[r] + p.w);
            acc = fmaf(fexp2(zp), cc, acc);
        }
    }
    #pragma unroll
    for (int o = 32; o > 0; o >>= 1) acc += __shfl_xor(acc, o);
    if (lane == 0) wsum[wave] = acc;
    __syncthreads();
    if (tid == 0) {
        atomicAdd(out, (wsum[0] + wsum[1] + wsum[2] + wsum[3]) * (1.0f / NB));
    }
}

// ---------------------------------------------------------------------------
extern "C" void kernel_launch(void* const* d_in, const int* in_sizes, int n_in,
                              void* d_out, int out_size, void* d_ws, size_t ws_size,
                              hipStream_t stream)
{
    const float* x = (const float*)d_in[0];
    const float* y = (const float*)d_in[1];
    float4* Px = (float4*)d_ws;            // [B][N] packed x-side
    float4* Py = Px + NB * NN;             // [B][M] packed y-side

    pack_init<<<(NB * NM + 255) / 256, 256, 0, stream>>>(y, Py, NB * NM);

    for (int it = 0; it < NITERS; ++it) {
        sink_update<<<NB * NN / 16, 256, 0, stream>>>(Py, x, Px);  // f-update
        sink_update<<<NB * NM / 16, 256, 0, stream>>>(Px, y, Py);  // g-update
    }

    hipMemsetAsync(d_out, 0, sizeof(float), stream);
    final_loss<<<NB * NN / 16, 256, 0, stream>>>(Px, Py, (float*)d_out);
}